// Round 1
// baseline (5668.843 us; speedup 1.0000x reference)
//
#include <hip/hip_runtime.h>
#include <hip/hip_bf16.h>

#define N_NODES 50000
#define D_FEAT 128
#define D_HID 128
#define N_CLASSES 64

// ---------------- degree / normalization ----------------

__global__ void init_deg(float* __restrict__ deg, int n) {
    int i = blockIdx.x * blockDim.x + threadIdx.x;
    if (i < n) deg[i] = 1.0f;  // self loop
}

__global__ void accum_deg(const int* __restrict__ src, const int* __restrict__ dst,
                          float* __restrict__ deg, int nEdges) {
    int e = blockIdx.x * blockDim.x + threadIdx.x;
    if (e >= nEdges) return;
    atomicAdd(&deg[src[e]], 1.0f);
    atomicAdd(&deg[dst[e]], 1.0f);
}

__global__ void rsqrt_inplace(float* __restrict__ deg, int n) {
    int i = blockIdx.x * blockDim.x + threadIdx.x;
    if (i < n) deg[i] = rsqrtf(deg[i]);
}

// ---------------- spmm ----------------

// y[i,f] = dinv[i]^2 * h[i,f]   (self-loop term; also initializes y)
template <int F>
__global__ void self_init(const float* __restrict__ h, const float* __restrict__ dinv,
                          float* __restrict__ y) {
    long gid = (long)blockIdx.x * blockDim.x + threadIdx.x;
    if (gid >= (long)N_NODES * F) return;
    int r = (int)(gid / F);
    float ds = dinv[r];
    y[gid] = ds * ds * h[gid];
}

// 32 threads per edge, float4 per thread (F==128)
__global__ void scatter_spmm(const int* __restrict__ src, const int* __restrict__ dst,
                             const float* __restrict__ dinv,
                             const float* __restrict__ hin, float* __restrict__ yout,
                             int nEdges) {
    long gid = (long)blockIdx.x * blockDim.x + threadIdx.x;
    int e  = (int)(gid >> 5);
    int f4 = (int)(gid & 31);
    if (e >= nEdges) return;
    int s = src[e], d = dst[e];
    float w = dinv[s] * dinv[d];
    const float4 vs = ((const float4*)(hin + (size_t)s * 128))[f4];
    const float4 vd = ((const float4*)(hin + (size_t)d * 128))[f4];
    float* ys = yout + (size_t)s * 128 + f4 * 4;
    float* yd = yout + (size_t)d * 128 + f4 * 4;
    atomicAdd(ys + 0, w * vd.x);
    atomicAdd(ys + 1, w * vd.y);
    atomicAdd(ys + 2, w * vd.z);
    atomicAdd(ys + 3, w * vd.w);
    atomicAdd(yd + 0, w * vs.x);
    atomicAdd(yd + 1, w * vs.y);
    atomicAdd(yd + 2, w * vs.z);
    atomicAdd(yd + 3, w * vs.w);
}

// ---------------- dense layers ----------------

// H[r,t] = relu(sum_k A[r,k] * W[k,t]),  A: [N,128], W: [128,128]
__global__ void gemm_relu(const float* __restrict__ A, const float* __restrict__ W,
                          float* __restrict__ H) {
    __shared__ float row[128];
    int r = blockIdx.x;
    int t = threadIdx.x;
    row[t] = A[(size_t)r * 128 + t];
    __syncthreads();
    float acc = 0.0f;
#pragma unroll
    for (int k = 0; k < 128; ++k) acc = fmaf(row[k], W[k * 128 + t], acc);
    H[(size_t)r * 128 + t] = fmaxf(acc, 0.0f);
}

// O[r,t] = sum_k A[r,k] * W[k,t],  A: [N,128], W: [128,64]
__global__ void gemm_out(const float* __restrict__ A, const float* __restrict__ W,
                         float* __restrict__ O) {
    __shared__ float row[128];
    int r = blockIdx.x;
    int t = threadIdx.x;  // blockDim = 64
    row[t] = A[(size_t)r * 128 + t];
    row[t + 64] = A[(size_t)r * 128 + t + 64];
    __syncthreads();
    float acc = 0.0f;
#pragma unroll
    for (int k = 0; k < 128; ++k) acc = fmaf(row[k], W[k * 64 + t], acc);
    O[(size_t)r * 64 + t] = acc;
}

// ---------------- launch ----------------

extern "C" void kernel_launch(void* const* d_in, const int* in_sizes, int n_in,
                              void* d_out, int out_size, void* d_ws, size_t ws_size,
                              hipStream_t stream) {
    const float* x  = (const float*)d_in[0];
    const float* W0 = (const float*)d_in[1];
    const float* W1 = (const float*)d_in[2];
    const int* edge = (const int*)d_in[3];
    const int E = in_sizes[3] / 2;
    const int N = N_NODES;
    const int* src = edge;
    const int* dst = edge + E;

    char* ws = (char*)d_ws;
    float* dinv = (float*)ws;                       // N floats
    size_t off = ((size_t)N * sizeof(float) + 255) & ~(size_t)255;
    float* bufA = (float*)(ws + off);               // N*128 floats
    float* bufB = (float*)(ws + off + (size_t)N * 128 * sizeof(float));

    float* out = (float*)d_out;

    // degrees -> dinv
    init_deg<<<(N + 255) / 256, 256, 0, stream>>>(dinv, N);
    accum_deg<<<(E + 255) / 256, 256, 0, stream>>>(src, dst, dinv, E);
    rsqrt_inplace<<<(N + 255) / 256, 256, 0, stream>>>(dinv, N);

    // layer 1: y1 = Â x  (bufA), h = relu(y1 @ W0) (bufB)
    {
        long tot = (long)N * 128;
        self_init<128><<<(int)((tot + 255) / 256), 256, 0, stream>>>(x, dinv, bufA);
        long sc = (long)E * 32;
        scatter_spmm<<<(int)((sc + 255) / 256), 256, 0, stream>>>(src, dst, dinv, x, bufA, E);
        gemm_relu<<<N, 128, 0, stream>>>(bufA, W0, bufB);
    }

    // layer 2: y2 = Â h (bufA), out = y2 @ W1
    {
        long tot = (long)N * 128;
        self_init<128><<<(int)((tot + 255) / 256), 256, 0, stream>>>(bufB, dinv, bufA);
        long sc = (long)E * 32;
        scatter_spmm<<<(int)((sc + 255) / 256), 256, 0, stream>>>(src, dst, dinv, bufB, bufA, E);
        gemm_out<<<N, 64, 0, stream>>>(bufA, W1, out);
    }
}

// Round 3
// 1424.023 us; speedup vs baseline: 3.9809x; 3.9809x over previous
//
#include <hip/hip_runtime.h>
#include <hip/hip_bf16.h>

#define N_NODES 50000

// ---------------- CSR build ----------------

__global__ void zero_cnt(int* __restrict__ cnt, int n) {
    int i = blockIdx.x * blockDim.x + threadIdx.x;
    if (i < n) cnt[i] = 0;
}

__global__ void count_deg(const int* __restrict__ src, const int* __restrict__ dst,
                          int* __restrict__ cnt, int nEdges) {
    int e = blockIdx.x * blockDim.x + threadIdx.x;
    if (e >= nEdges) return;
    atomicAdd(&cnt[src[e]], 1);
    atomicAdd(&cnt[dst[e]], 1);
}

// single block, 1024 threads: exclusive scan of cnt -> rowptr/cursor, and dinv
__global__ void scan_rowptr(const int* __restrict__ cnt, int* __restrict__ rowptr,
                            int* __restrict__ cursor, float* __restrict__ dinv, int n) {
    __shared__ int partial[1024];
    int t = threadIdx.x;
    const int chunk = (n + 1023) / 1024;
    int lo = t * chunk;
    int hi = lo + chunk; if (hi > n) hi = n; if (lo > n) lo = n;
    int s = 0;
    for (int i = lo; i < hi; ++i) s += cnt[i];
    partial[t] = s;
    __syncthreads();
    for (int d = 1; d < 1024; d <<= 1) {
        int v = (t >= d) ? partial[t - d] : 0;
        __syncthreads();
        partial[t] += v;
        __syncthreads();
    }
    int base = (t == 0) ? 0 : partial[t - 1];
    for (int i = lo; i < hi; ++i) {
        rowptr[i] = base;
        cursor[i] = base;
        dinv[i] = rsqrtf((float)cnt[i] + 1.0f);  // +1 self loop
        base += cnt[i];
    }
    if (t == 1023) rowptr[n] = partial[1023];
}

__global__ void build_cols(const int* __restrict__ src, const int* __restrict__ dst,
                           int* __restrict__ cursor, int* __restrict__ col, int nEdges) {
    int e = blockIdx.x * blockDim.x + threadIdx.x;
    if (e >= nEdges) return;
    int s = src[e], d = dst[e];
    int ps = atomicAdd(&cursor[s], 1);
    col[ps] = d;
    int pd = atomicAdd(&cursor[d], 1);
    col[pd] = s;
}

// ---------------- gather SpMM, F=128 ----------------
// one wave per row; two half-waves process alternating neighbors; float4/lane
__global__ void gather_spmm128(const int* __restrict__ rowptr, const int* __restrict__ col,
                               const float* __restrict__ dinv, const float* __restrict__ h,
                               float* __restrict__ y) {
    int wave = (int)((blockIdx.x * (unsigned)blockDim.x + threadIdx.x) >> 6);
    if (wave >= N_NODES) return;
    int lane = threadIdx.x & 63;
    int half = lane >> 5;
    int f4 = lane & 31;
    int r = wave;
    float dr = dinv[r];
    int beg = rowptr[r], end = rowptr[r + 1];
    float4 acc = make_float4(0.f, 0.f, 0.f, 0.f);
    for (int j = beg + half; j < end; j += 2) {
        int c = col[j];
        float w = dr * dinv[c];
        float4 v = ((const float4*)(h + (size_t)c * 128))[f4];
        acc.x = fmaf(w, v.x, acc.x);
        acc.y = fmaf(w, v.y, acc.y);
        acc.z = fmaf(w, v.z, acc.z);
        acc.w = fmaf(w, v.w, acc.w);
    }
    acc.x += __shfl_xor(acc.x, 32);
    acc.y += __shfl_xor(acc.y, 32);
    acc.z += __shfl_xor(acc.z, 32);
    acc.w += __shfl_xor(acc.w, 32);
    if (half == 0) {
        float4 v = ((const float4*)(h + (size_t)r * 128))[f4];
        float w = dr * dr;
        acc.x = fmaf(w, v.x, acc.x);
        acc.y = fmaf(w, v.y, acc.y);
        acc.z = fmaf(w, v.z, acc.z);
        acc.w = fmaf(w, v.w, acc.w);
        ((float4*)(y + (size_t)r * 128))[f4] = acc;
    }
}

// ---------------- gather SpMM, F=64 ----------------
// one wave per row; 4 groups of 16 lanes process alternating neighbors
__global__ void gather_spmm64(const int* __restrict__ rowptr, const int* __restrict__ col,
                              const float* __restrict__ dinv, const float* __restrict__ h,
                              float* __restrict__ y) {
    int wave = (int)((blockIdx.x * (unsigned)blockDim.x + threadIdx.x) >> 6);
    if (wave >= N_NODES) return;
    int lane = threadIdx.x & 63;
    int g = lane >> 4;    // 0..3
    int f4 = lane & 15;   // float4 slot 0..15
    int r = wave;
    float dr = dinv[r];
    int beg = rowptr[r], end = rowptr[r + 1];
    float4 acc = make_float4(0.f, 0.f, 0.f, 0.f);
    for (int j = beg + g; j < end; j += 4) {
        int c = col[j];
        float w = dr * dinv[c];
        float4 v = ((const float4*)(h + (size_t)c * 64))[f4];
        acc.x = fmaf(w, v.x, acc.x);
        acc.y = fmaf(w, v.y, acc.y);
        acc.z = fmaf(w, v.z, acc.z);
        acc.w = fmaf(w, v.w, acc.w);
    }
    acc.x += __shfl_xor(acc.x, 16);
    acc.y += __shfl_xor(acc.y, 16);
    acc.z += __shfl_xor(acc.z, 16);
    acc.w += __shfl_xor(acc.w, 16);
    acc.x += __shfl_xor(acc.x, 32);
    acc.y += __shfl_xor(acc.y, 32);
    acc.z += __shfl_xor(acc.z, 32);
    acc.w += __shfl_xor(acc.w, 32);
    if (g == 0) {
        float4 v = ((const float4*)(h + (size_t)r * 64))[f4];
        float w = dr * dr;
        acc.x = fmaf(w, v.x, acc.x);
        acc.y = fmaf(w, v.y, acc.y);
        acc.z = fmaf(w, v.z, acc.z);
        acc.w = fmaf(w, v.w, acc.w);
        ((float4*)(y + (size_t)r * 64))[f4] = acc;
    }
}

// ---------------- dense layers ----------------

// In-place-safe 128x128 GEMM + ReLU: one block owns 16 rows and ALL 128 cols.
// A and O may alias (all global reads of A happen before any write of O).
__global__ void gemm128_relu(const float* __restrict__ A, const float* __restrict__ W,
                             float* __restrict__ O) {
    __shared__ float Wl[128 * 64];   // one 64-col half of W at a time
    __shared__ float Rl[16][132];    // 16 rows, padded
    int t = threadIdx.x;
    int rbase = blockIdx.x * 16;     // 50000 % 16 == 0
    for (int i = t; i < 512; i += 256) {         // 16 rows * 32 float4
        int rr = i >> 5;
        int kg = i & 31;
        *(float4*)&Rl[rr][kg * 4] = *(const float4*)&A[(size_t)(rbase + rr) * 128 + kg * 4];
    }
    int c4 = t & 15;   // float4 col group within 64-col half
    int rg = t >> 4;   // row 0..15
    float4 accs[2];
#pragma unroll
    for (int half = 0; half < 2; ++half) {
        __syncthreads();                          // protect Wl reuse
        int c0 = half * 64;
        for (int i = t; i < 2048; i += 256) {     // 128x64 floats = 2048 float4
            int k = i >> 4;
            int cg = i & 15;
            *(float4*)&Wl[k * 64 + cg * 4] = *(const float4*)&W[k * 128 + c0 + cg * 4];
        }
        __syncthreads();
        float4 acc = make_float4(0.f, 0.f, 0.f, 0.f);
#pragma unroll
        for (int k4 = 0; k4 < 32; ++k4) {
            float4 rv = *(const float4*)&Rl[rg][k4 * 4];
            float4 w0 = *(const float4*)&Wl[(k4 * 4 + 0) * 64 + c4 * 4];
            float4 w1 = *(const float4*)&Wl[(k4 * 4 + 1) * 64 + c4 * 4];
            float4 w2 = *(const float4*)&Wl[(k4 * 4 + 2) * 64 + c4 * 4];
            float4 w3 = *(const float4*)&Wl[(k4 * 4 + 3) * 64 + c4 * 4];
            acc.x = fmaf(rv.x, w0.x, acc.x); acc.y = fmaf(rv.x, w0.y, acc.y);
            acc.z = fmaf(rv.x, w0.z, acc.z); acc.w = fmaf(rv.x, w0.w, acc.w);
            acc.x = fmaf(rv.y, w1.x, acc.x); acc.y = fmaf(rv.y, w1.y, acc.y);
            acc.z = fmaf(rv.y, w1.z, acc.z); acc.w = fmaf(rv.y, w1.w, acc.w);
            acc.x = fmaf(rv.z, w2.x, acc.x); acc.y = fmaf(rv.z, w2.y, acc.y);
            acc.z = fmaf(rv.z, w2.z, acc.z); acc.w = fmaf(rv.z, w2.w, acc.w);
            acc.x = fmaf(rv.w, w3.x, acc.x); acc.y = fmaf(rv.w, w3.y, acc.y);
            acc.z = fmaf(rv.w, w3.z, acc.z); acc.w = fmaf(rv.w, w3.w, acc.w);
        }
        accs[half] = acc;
    }
#pragma unroll
    for (int half = 0; half < 2; ++half) {
        float4 acc = accs[half];
        acc.x = fmaxf(acc.x, 0.f); acc.y = fmaxf(acc.y, 0.f);
        acc.z = fmaxf(acc.z, 0.f); acc.w = fmaxf(acc.w, 0.f);
        *(float4*)&O[(size_t)(rbase + rg) * 128 + half * 64 + c4 * 4] = acc;
    }
}

// O[N,64] = A[N,128] @ W[128,64]  (separate output buffer)
__global__ void gemm64(const float* __restrict__ A, const float* __restrict__ W,
                       float* __restrict__ O) {
    __shared__ float Wl[128 * 64];
    __shared__ float Rl[16][132];
    int t = threadIdx.x;
    int rbase = blockIdx.x * 16;
    for (int i = t; i < 2048; i += 256) {
        int k = i >> 4;
        int cg = i & 15;
        *(float4*)&Wl[k * 64 + cg * 4] = *(const float4*)&W[k * 64 + cg * 4];
    }
    for (int i = t; i < 512; i += 256) {
        int rr = i >> 5;
        int kg = i & 31;
        *(float4*)&Rl[rr][kg * 4] = *(const float4*)&A[(size_t)(rbase + rr) * 128 + kg * 4];
    }
    __syncthreads();
    int c4 = t & 15;
    int rg = t >> 4;
    float4 acc = make_float4(0.f, 0.f, 0.f, 0.f);
#pragma unroll
    for (int k4 = 0; k4 < 32; ++k4) {
        float4 rv = *(const float4*)&Rl[rg][k4 * 4];
        float4 w0 = *(const float4*)&Wl[(k4 * 4 + 0) * 64 + c4 * 4];
        float4 w1 = *(const float4*)&Wl[(k4 * 4 + 1) * 64 + c4 * 4];
        float4 w2 = *(const float4*)&Wl[(k4 * 4 + 2) * 64 + c4 * 4];
        float4 w3 = *(const float4*)&Wl[(k4 * 4 + 3) * 64 + c4 * 4];
        acc.x = fmaf(rv.x, w0.x, acc.x); acc.y = fmaf(rv.x, w0.y, acc.y);
        acc.z = fmaf(rv.x, w0.z, acc.z); acc.w = fmaf(rv.x, w0.w, acc.w);
        acc.x = fmaf(rv.y, w1.x, acc.x); acc.y = fmaf(rv.y, w1.y, acc.y);
        acc.z = fmaf(rv.y, w1.z, acc.z); acc.w = fmaf(rv.y, w1.w, acc.w);
        acc.x = fmaf(rv.z, w2.x, acc.x); acc.y = fmaf(rv.z, w2.y, acc.y);
        acc.z = fmaf(rv.z, w2.z, acc.z); acc.w = fmaf(rv.z, w2.w, acc.w);
        acc.x = fmaf(rv.w, w3.x, acc.x); acc.y = fmaf(rv.w, w3.y, acc.y);
        acc.z = fmaf(rv.w, w3.z, acc.z); acc.w = fmaf(rv.w, w3.w, acc.w);
    }
    *(float4*)&O[(size_t)(rbase + rg) * 64 + c4 * 4] = acc;
}

// ---------------- launch ----------------

extern "C" void kernel_launch(void* const* d_in, const int* in_sizes, int n_in,
                              void* d_out, int out_size, void* d_ws, size_t ws_size,
                              hipStream_t stream) {
    const float* x  = (const float*)d_in[0];
    const float* W0 = (const float*)d_in[1];
    const float* W1 = (const float*)d_in[2];
    const int* edge = (const int*)d_in[3];
    const int E = in_sizes[3] / 2;
    const int N = N_NODES;
    const int* src = edge;
    const int* dst = edge + E;

    auto align256 = [](size_t v) { return (v + 255) & ~(size_t)255; };
    char* ws = (char*)d_ws;
    size_t off = 0;
    int* rowptr  = (int*)(ws + off);   off += align256((size_t)(N + 1) * 4);
    float* dinv  = (float*)(ws + off); off += align256((size_t)N * 4);
    int* colidx  = (int*)(ws + off);   off += align256((size_t)2 * E * 4);
    float* bufA  = (float*)(ws + off); off += align256((size_t)N * 128 * 4);  // N x 128
    float* bufB  = (float*)(ws + off); off += align256((size_t)N * 64 * 4);   // N x 64
    // cnt/cursor alias into bufA (consumed before first spmm writes bufA)
    int* cnt    = (int*)bufA;
    int* cursor = (int*)bufA + N;

    float* out = (float*)d_out;

    // CSR build
    zero_cnt<<<(N + 255) / 256, 256, 0, stream>>>(cnt, N);
    count_deg<<<(E + 255) / 256, 256, 0, stream>>>(src, dst, cnt, E);
    scan_rowptr<<<1, 1024, 0, stream>>>(cnt, rowptr, cursor, dinv, N);
    build_cols<<<(E + 255) / 256, 256, 0, stream>>>(src, dst, cursor, colidx, E);

    const int spmm_blocks = (N * 64 + 255) / 256;

    // layer 1: bufA = Â x ; bufA = relu(bufA @ W0)  (in-place-safe GEMM)
    gather_spmm128<<<spmm_blocks, 256, 0, stream>>>(rowptr, colidx, dinv, x, bufA);
    gemm128_relu<<<N / 16, 256, 0, stream>>>(bufA, W0, bufA);

    // layer 2: bufB = bufA @ W1 ; out = Â bufB   (associativity: spmm(h)@W1 == Â(h@W1))
    gemm64<<<N / 16, 256, 0, stream>>>(bufA, W1, bufB);
    gather_spmm64<<<spmm_blocks, 256, 0, stream>>>(rowptr, colidx, dinv, bufB, out);
}

// Round 4
// 637.695 us; speedup vs baseline: 8.8896x; 2.2331x over previous
//
#include <hip/hip_runtime.h>
#include <hip/hip_bf16.h>

#define N_NODES 50000

// ---------------- CSR build ----------------

__global__ void zero_cnt(int* __restrict__ cnt, int n) {
    int i = blockIdx.x * blockDim.x + threadIdx.x;
    if (i < n) cnt[i] = 0;
}

__global__ void count_deg(const int* __restrict__ src, const int* __restrict__ dst,
                          int* __restrict__ cnt, int nEdges) {
    int e = blockIdx.x * blockDim.x + threadIdx.x;
    if (e >= nEdges) return;
    atomicAdd(&cnt[src[e]], 1);
    atomicAdd(&cnt[dst[e]], 1);
}

// single block, 1024 threads: exclusive scan of cnt -> rowptr/cursor, and dinv
__global__ void scan_rowptr(const int* __restrict__ cnt, int* __restrict__ rowptr,
                            int* __restrict__ cursor, float* __restrict__ dinv, int n) {
    __shared__ int partial[1024];
    int t = threadIdx.x;
    const int chunk = (n + 1023) / 1024;
    int lo = t * chunk;
    int hi = lo + chunk; if (hi > n) hi = n; if (lo > n) lo = n;
    int s = 0;
    for (int i = lo; i < hi; ++i) s += cnt[i];
    partial[t] = s;
    __syncthreads();
    for (int d = 1; d < 1024; d <<= 1) {
        int v = (t >= d) ? partial[t - d] : 0;
        __syncthreads();
        partial[t] += v;
        __syncthreads();
    }
    int base = (t == 0) ? 0 : partial[t - 1];
    for (int i = lo; i < hi; ++i) {
        rowptr[i] = base;
        cursor[i] = base;
        dinv[i] = rsqrtf((float)cnt[i] + 1.0f);  // +1 self loop
        base += cnt[i];
    }
    if (t == 1023) rowptr[n] = partial[1023];
}

__global__ void build_cols(const int* __restrict__ src, const int* __restrict__ dst,
                           int* __restrict__ cursor, int* __restrict__ col, int nEdges) {
    int e = blockIdx.x * blockDim.x + threadIdx.x;
    if (e >= nEdges) return;
    int s = src[e], d = dst[e];
    int ps = atomicAdd(&cursor[s], 1);
    col[ps] = d;
    int pd = atomicAdd(&cursor[d], 1);
    col[pd] = s;
}

// ---------------- gather SpMM, F=128 ----------------
// one wave per row; two half-waves process alternating neighbors; float4/lane
__global__ void gather_spmm128(const int* __restrict__ rowptr, const int* __restrict__ col,
                               const float* __restrict__ dinv, const float* __restrict__ h,
                               float* __restrict__ y) {
    int wave = (int)((blockIdx.x * (unsigned)blockDim.x + threadIdx.x) >> 6);
    if (wave >= N_NODES) return;
    int lane = threadIdx.x & 63;
    int half = lane >> 5;
    int f4 = lane & 31;
    int r = wave;
    float dr = dinv[r];
    int beg = rowptr[r], end = rowptr[r + 1];
    float4 acc = make_float4(0.f, 0.f, 0.f, 0.f);
    for (int j = beg + half; j < end; j += 2) {
        int c = col[j];
        float w = dr * dinv[c];
        float4 v = ((const float4*)(h + (size_t)c * 128))[f4];
        acc.x = fmaf(w, v.x, acc.x);
        acc.y = fmaf(w, v.y, acc.y);
        acc.z = fmaf(w, v.z, acc.z);
        acc.w = fmaf(w, v.w, acc.w);
    }
    acc.x += __shfl_xor(acc.x, 32);
    acc.y += __shfl_xor(acc.y, 32);
    acc.z += __shfl_xor(acc.z, 32);
    acc.w += __shfl_xor(acc.w, 32);
    if (half == 0) {
        float4 v = ((const float4*)(h + (size_t)r * 128))[f4];
        float w = dr * dr;
        acc.x = fmaf(w, v.x, acc.x);
        acc.y = fmaf(w, v.y, acc.y);
        acc.z = fmaf(w, v.z, acc.z);
        acc.w = fmaf(w, v.w, acc.w);
        ((float4*)(y + (size_t)r * 128))[f4] = acc;
    }
}

// ---------------- gather SpMM, F=64 ----------------
// one wave per row; 4 groups of 16 lanes process alternating neighbors
__global__ void gather_spmm64(const int* __restrict__ rowptr, const int* __restrict__ col,
                              const float* __restrict__ dinv, const float* __restrict__ h,
                              float* __restrict__ y) {
    int wave = (int)((blockIdx.x * (unsigned)blockDim.x + threadIdx.x) >> 6);
    if (wave >= N_NODES) return;
    int lane = threadIdx.x & 63;
    int g = lane >> 4;    // 0..3
    int f4 = lane & 15;   // float4 slot 0..15
    int r = wave;
    float dr = dinv[r];
    int beg = rowptr[r], end = rowptr[r + 1];
    float4 acc = make_float4(0.f, 0.f, 0.f, 0.f);
    for (int j = beg + g; j < end; j += 4) {
        int c = col[j];
        float w = dr * dinv[c];
        float4 v = ((const float4*)(h + (size_t)c * 64))[f4];
        acc.x = fmaf(w, v.x, acc.x);
        acc.y = fmaf(w, v.y, acc.y);
        acc.z = fmaf(w, v.z, acc.z);
        acc.w = fmaf(w, v.w, acc.w);
    }
    acc.x += __shfl_xor(acc.x, 16);
    acc.y += __shfl_xor(acc.y, 16);
    acc.z += __shfl_xor(acc.z, 16);
    acc.w += __shfl_xor(acc.w, 16);
    acc.x += __shfl_xor(acc.x, 32);
    acc.y += __shfl_xor(acc.y, 32);
    acc.z += __shfl_xor(acc.z, 32);
    acc.w += __shfl_xor(acc.w, 32);
    if (g == 0) {
        float4 v = ((const float4*)(h + (size_t)r * 64))[f4];
        float w = dr * dr;
        acc.x = fmaf(w, v.x, acc.x);
        acc.y = fmaf(w, v.y, acc.y);
        acc.z = fmaf(w, v.z, acc.z);
        acc.w = fmaf(w, v.w, acc.w);
        ((float4*)(y + (size_t)r * 64))[f4] = acc;
    }
}

// ---------------- dense layers ----------------
// Register-blocked GEMM: O[nrows,COLS] = A[nrows,128] @ W[128,COLS], optional ReLU.
// 32-row tile per block, 256 threads. A staged in LDS (broadcast reads);
// W read straight from global (hits L2: total W traffic ~100 MB @ 34.5 TB/s).
// O may alias A (each block reads only its own 32 rows, all before any write).
// __launch_bounds__(256,2): 256-VGPR budget — no spill (round-3's 830us kernel
// was scratch-bound: VGPR capped at 64, 1.7 GB of phantom WRITE_SIZE).
template <int COLS, bool RELU>
__global__ __launch_bounds__(256, 2)
void gemm_rb(const float* A, const float* __restrict__ W, float* O, int nrows) {
    constexpr int CG  = COLS / 4;   // float4 col groups (32 or 16)
    constexpr int RPT = COLS / 32;  // rows per thread (4 or 2)
    __shared__ float At[32][132];
    int t = threadIdx.x;
    int rbase = blockIdx.x * 32;
    // stage A tile: 32 rows x 128 cols = 1024 float4
    for (int i = t; i < 1024; i += 256) {
        int rr = i >> 5;
        int kg = i & 31;
        int r = rbase + rr;
        float4 v = (r < nrows) ? ((const float4*)(A + (size_t)r * 128))[kg]
                               : make_float4(0.f, 0.f, 0.f, 0.f);
        *(float4*)&At[rr][kg * 4] = v;
    }
    __syncthreads();
    int c4 = t % CG;
    int rg = t / CG;
    float4 acc[RPT];
#pragma unroll
    for (int i = 0; i < RPT; ++i) acc[i] = make_float4(0.f, 0.f, 0.f, 0.f);
    const float* Wp = W + c4 * 4;
#pragma unroll 8
    for (int k = 0; k < 128; ++k) {
        float4 w = *(const float4*)(Wp + (size_t)k * COLS);
#pragma unroll
        for (int i = 0; i < RPT; ++i) {
            float a = At[rg * RPT + i][k];
            acc[i].x = fmaf(a, w.x, acc[i].x);
            acc[i].y = fmaf(a, w.y, acc[i].y);
            acc[i].z = fmaf(a, w.z, acc[i].z);
            acc[i].w = fmaf(a, w.w, acc[i].w);
        }
    }
#pragma unroll
    for (int i = 0; i < RPT; ++i) {
        int r = rbase + rg * RPT + i;
        if (r < nrows) {
            float4 v = acc[i];
            if (RELU) {
                v.x = fmaxf(v.x, 0.f); v.y = fmaxf(v.y, 0.f);
                v.z = fmaxf(v.z, 0.f); v.w = fmaxf(v.w, 0.f);
            }
            *(float4*)(O + (size_t)r * COLS + c4 * 4) = v;
        }
    }
}

// ---------------- launch ----------------

extern "C" void kernel_launch(void* const* d_in, const int* in_sizes, int n_in,
                              void* d_out, int out_size, void* d_ws, size_t ws_size,
                              hipStream_t stream) {
    const float* x  = (const float*)d_in[0];
    const float* W0 = (const float*)d_in[1];
    const float* W1 = (const float*)d_in[2];
    const int* edge = (const int*)d_in[3];
    const int E = in_sizes[3] / 2;
    const int N = N_NODES;
    const int* src = edge;
    const int* dst = edge + E;

    auto align256 = [](size_t v) { return (v + 255) & ~(size_t)255; };
    char* ws = (char*)d_ws;
    size_t off = 0;
    int* rowptr  = (int*)(ws + off);   off += align256((size_t)(N + 1) * 4);
    float* dinv  = (float*)(ws + off); off += align256((size_t)N * 4);
    int* colidx  = (int*)(ws + off);   off += align256((size_t)2 * E * 4);
    float* bufA  = (float*)(ws + off); off += align256((size_t)N * 128 * 4);  // N x 128
    float* bufB  = (float*)(ws + off); off += align256((size_t)N * 64 * 4);   // N x 64
    // cnt/cursor alias into bufA (consumed before first spmm writes bufA)
    int* cnt    = (int*)bufA;
    int* cursor = (int*)bufA + N;

    float* out = (float*)d_out;

    // CSR build
    zero_cnt<<<(N + 255) / 256, 256, 0, stream>>>(cnt, N);
    count_deg<<<(E + 255) / 256, 256, 0, stream>>>(src, dst, cnt, E);
    scan_rowptr<<<1, 1024, 0, stream>>>(cnt, rowptr, cursor, dinv, N);
    build_cols<<<(E + 255) / 256, 256, 0, stream>>>(src, dst, cursor, colidx, E);

    const int spmm_blocks = (N * 64 + 255) / 256;
    const int gemm_blocks = (N + 31) / 32;

    // layer 1: bufA = Â x ; bufA = relu(bufA @ W0)  (in-place-safe GEMM)
    gather_spmm128<<<spmm_blocks, 256, 0, stream>>>(rowptr, colidx, dinv, x, bufA);
    gemm_rb<128, true><<<gemm_blocks, 256, 0, stream>>>(bufA, W0, bufA, N);

    // layer 2: bufB = bufA @ W1 ; out = Â bufB   (associativity: spmm(h)@W1 == Â(h@W1))
    gemm_rb<64, false><<<gemm_blocks, 256, 0, stream>>>(bufA, W1, bufB, N);
    gather_spmm64<<<spmm_blocks, 256, 0, stream>>>(rowptr, colidx, dinv, bufB, out);
}

// Round 5
// 486.540 us; speedup vs baseline: 11.6514x; 1.3107x over previous
//
#include <hip/hip_runtime.h>
#include <hip/hip_bf16.h>

#define N_NODES 50000
#define NPASS 8

// ---------------- CSR build ----------------

__global__ void zero_cnt(int* __restrict__ cnt, int n) {
    int i = blockIdx.x * blockDim.x + threadIdx.x;
    if (i < n) cnt[i] = 0;
}

__global__ void count_deg(const int* __restrict__ src, const int* __restrict__ dst,
                          int* __restrict__ cnt, int nEdges) {
    int e = blockIdx.x * blockDim.x + threadIdx.x;
    if (e >= nEdges) return;
    atomicAdd(&cnt[src[e]], 1);
    atomicAdd(&cnt[dst[e]], 1);
}

// --- 3-kernel scan: cnt -> rowptr/cursor (+dinv) ---

__global__ void partial_sum(const int* __restrict__ cnt, int* __restrict__ bsum, int n) {
    __shared__ int sh[256];
    int t = threadIdx.x;
    int i = blockIdx.x * 256 + t;
    sh[t] = (i < n) ? cnt[i] : 0;
    __syncthreads();
    for (int d = 128; d > 0; d >>= 1) {
        if (t < d) sh[t] += sh[t + d];
        __syncthreads();
    }
    if (t == 0) bsum[blockIdx.x] = sh[0];
}

// 1 block, 256 threads; nb <= 256. Exclusive-scans bsum in place, writes total.
__global__ void scan_bsums(int* __restrict__ bsum, int* __restrict__ total_out, int nb) {
    __shared__ int sh[256];
    int t = threadIdx.x;
    int v = (t < nb) ? bsum[t] : 0;
    sh[t] = v;
    __syncthreads();
    for (int d = 1; d < 256; d <<= 1) {
        int u = (t >= d) ? sh[t - d] : 0;
        __syncthreads();
        sh[t] += u;
        __syncthreads();
    }
    if (t < nb) bsum[t] = sh[t] - v;          // exclusive prefix
    if (t == nb - 1) *total_out = sh[t];      // rowptr[N]
}

__global__ void write_rowptr(const int* __restrict__ cnt, const int* __restrict__ bsum,
                             int* __restrict__ rowptr, int* __restrict__ cursor,
                             float* __restrict__ dinv, int n) {
    __shared__ int sh[256];
    int t = threadIdx.x;
    int i = blockIdx.x * 256 + t;
    int v = (i < n) ? cnt[i] : 0;
    sh[t] = v;
    __syncthreads();
    for (int d = 1; d < 256; d <<= 1) {
        int u = (t >= d) ? sh[t - d] : 0;
        __syncthreads();
        sh[t] += u;
        __syncthreads();
    }
    if (i < n) {
        int excl = sh[t] - v + bsum[blockIdx.x];
        rowptr[i] = excl;
        cursor[i] = excl;
        dinv[i] = rsqrtf((float)v + 1.0f);  // +1 self loop
    }
}

// windowed column scatter: only place entries for destination rows in [lo,hi)
// so col[] writes stay within a ~800 KB region that write-combines in L2.
__global__ void build_cols_win(const int* __restrict__ src, const int* __restrict__ dst,
                               int* __restrict__ cursor, int* __restrict__ col,
                               int nEdges, int lo, int hi) {
    int e = blockIdx.x * blockDim.x + threadIdx.x;
    if (e >= nEdges) return;
    int s = src[e], d = dst[e];
    if (s >= lo && s < hi) col[atomicAdd(&cursor[s], 1)] = d;
    if (d >= lo && d < hi) col[atomicAdd(&cursor[d], 1)] = s;
}

// ---------------- gather SpMM, F=128 ----------------
// one wave per row; two half-waves process alternating neighbors; float4/lane
__global__ void gather_spmm128(const int* __restrict__ rowptr, const int* __restrict__ col,
                               const float* __restrict__ dinv, const float* __restrict__ h,
                               float* __restrict__ y) {
    int wave = (int)((blockIdx.x * (unsigned)blockDim.x + threadIdx.x) >> 6);
    if (wave >= N_NODES) return;
    int lane = threadIdx.x & 63;
    int half = lane >> 5;
    int f4 = lane & 31;
    int r = wave;
    float dr = dinv[r];
    int beg = rowptr[r], end = rowptr[r + 1];
    float4 acc = make_float4(0.f, 0.f, 0.f, 0.f);
    for (int j = beg + half; j < end; j += 2) {
        int c = col[j];
        float w = dr * dinv[c];
        float4 v = ((const float4*)(h + (size_t)c * 128))[f4];
        acc.x = fmaf(w, v.x, acc.x);
        acc.y = fmaf(w, v.y, acc.y);
        acc.z = fmaf(w, v.z, acc.z);
        acc.w = fmaf(w, v.w, acc.w);
    }
    acc.x += __shfl_xor(acc.x, 32);
    acc.y += __shfl_xor(acc.y, 32);
    acc.z += __shfl_xor(acc.z, 32);
    acc.w += __shfl_xor(acc.w, 32);
    if (half == 0) {
        float4 v = ((const float4*)(h + (size_t)r * 128))[f4];
        float w = dr * dr;
        acc.x = fmaf(w, v.x, acc.x);
        acc.y = fmaf(w, v.y, acc.y);
        acc.z = fmaf(w, v.z, acc.z);
        acc.w = fmaf(w, v.w, acc.w);
        ((float4*)(y + (size_t)r * 128))[f4] = acc;
    }
}

// ---------------- gather SpMM, F=64 ----------------
// one wave per row; 4 groups of 16 lanes process alternating neighbors
__global__ void gather_spmm64(const int* __restrict__ rowptr, const int* __restrict__ col,
                              const float* __restrict__ dinv, const float* __restrict__ h,
                              float* __restrict__ y) {
    int wave = (int)((blockIdx.x * (unsigned)blockDim.x + threadIdx.x) >> 6);
    if (wave >= N_NODES) return;
    int lane = threadIdx.x & 63;
    int g = lane >> 4;    // 0..3
    int f4 = lane & 15;   // float4 slot 0..15
    int r = wave;
    float dr = dinv[r];
    int beg = rowptr[r], end = rowptr[r + 1];
    float4 acc = make_float4(0.f, 0.f, 0.f, 0.f);
    for (int j = beg + g; j < end; j += 4) {
        int c = col[j];
        float w = dr * dinv[c];
        float4 v = ((const float4*)(h + (size_t)c * 64))[f4];
        acc.x = fmaf(w, v.x, acc.x);
        acc.y = fmaf(w, v.y, acc.y);
        acc.z = fmaf(w, v.z, acc.z);
        acc.w = fmaf(w, v.w, acc.w);
    }
    acc.x += __shfl_xor(acc.x, 16);
    acc.y += __shfl_xor(acc.y, 16);
    acc.z += __shfl_xor(acc.z, 16);
    acc.w += __shfl_xor(acc.w, 16);
    acc.x += __shfl_xor(acc.x, 32);
    acc.y += __shfl_xor(acc.y, 32);
    acc.z += __shfl_xor(acc.z, 32);
    acc.w += __shfl_xor(acc.w, 32);
    if (g == 0) {
        float4 v = ((const float4*)(h + (size_t)r * 64))[f4];
        float w = dr * dr;
        acc.x = fmaf(w, v.x, acc.x);
        acc.y = fmaf(w, v.y, acc.y);
        acc.z = fmaf(w, v.z, acc.z);
        acc.w = fmaf(w, v.w, acc.w);
        ((float4*)(y + (size_t)r * 64))[f4] = acc;
    }
}

// ---------------- dense layers ----------------
// Register-blocked GEMM: O[nrows,COLS] = A[nrows,128] @ W[128,COLS], optional ReLU.
// 32-row tile per block, 256 threads. A staged in LDS (broadcast reads);
// W read straight from global (hits L2). O may alias A.
template <int COLS, bool RELU>
__global__ __launch_bounds__(256, 2)
void gemm_rb(const float* A, const float* __restrict__ W, float* O, int nrows) {
    constexpr int CG  = COLS / 4;   // float4 col groups (32 or 16)
    constexpr int RPT = COLS / 32;  // rows per thread (4 or 2)
    __shared__ float At[32][132];
    int t = threadIdx.x;
    int rbase = blockIdx.x * 32;
    for (int i = t; i < 1024; i += 256) {
        int rr = i >> 5;
        int kg = i & 31;
        int r = rbase + rr;
        float4 v = (r < nrows) ? ((const float4*)(A + (size_t)r * 128))[kg]
                               : make_float4(0.f, 0.f, 0.f, 0.f);
        *(float4*)&At[rr][kg * 4] = v;
    }
    __syncthreads();
    int c4 = t % CG;
    int rg = t / CG;
    float4 acc[RPT];
#pragma unroll
    for (int i = 0; i < RPT; ++i) acc[i] = make_float4(0.f, 0.f, 0.f, 0.f);
    const float* Wp = W + c4 * 4;
#pragma unroll 8
    for (int k = 0; k < 128; ++k) {
        float4 w = *(const float4*)(Wp + (size_t)k * COLS);
#pragma unroll
        for (int i = 0; i < RPT; ++i) {
            float a = At[rg * RPT + i][k];
            acc[i].x = fmaf(a, w.x, acc[i].x);
            acc[i].y = fmaf(a, w.y, acc[i].y);
            acc[i].z = fmaf(a, w.z, acc[i].z);
            acc[i].w = fmaf(a, w.w, acc[i].w);
        }
    }
#pragma unroll
    for (int i = 0; i < RPT; ++i) {
        int r = rbase + rg * RPT + i;
        if (r < nrows) {
            float4 v = acc[i];
            if (RELU) {
                v.x = fmaxf(v.x, 0.f); v.y = fmaxf(v.y, 0.f);
                v.z = fmaxf(v.z, 0.f); v.w = fmaxf(v.w, 0.f);
            }
            *(float4*)(O + (size_t)r * COLS + c4 * 4) = v;
        }
    }
}

// ---------------- launch ----------------

extern "C" void kernel_launch(void* const* d_in, const int* in_sizes, int n_in,
                              void* d_out, int out_size, void* d_ws, size_t ws_size,
                              hipStream_t stream) {
    const float* x  = (const float*)d_in[0];
    const float* W0 = (const float*)d_in[1];
    const float* W1 = (const float*)d_in[2];
    const int* edge = (const int*)d_in[3];
    const int E = in_sizes[3] / 2;
    const int N = N_NODES;
    const int* src = edge;
    const int* dst = edge + E;

    auto align256 = [](size_t v) { return (v + 255) & ~(size_t)255; };
    char* ws = (char*)d_ws;
    size_t off = 0;
    int* rowptr  = (int*)(ws + off);   off += align256((size_t)(N + 1) * 4);
    float* dinv  = (float*)(ws + off); off += align256((size_t)N * 4);
    int* colidx  = (int*)(ws + off);   off += align256((size_t)2 * E * 4);
    float* bufA  = (float*)(ws + off); off += align256((size_t)N * 128 * 4);  // N x 128
    float* bufB  = (float*)(ws + off); off += align256((size_t)N * 64 * 4);   // N x 64
    // cnt/cursor/bsum alias into bufA (consumed before first spmm writes bufA)
    int* cnt    = (int*)bufA;
    int* cursor = (int*)bufA + N;
    int* bsum   = (int*)bufA + 2 * N;

    float* out = (float*)d_out;

    const int nb = (N + 255) / 256;  // 196 scan blocks

    // CSR build
    zero_cnt<<<nb, 256, 0, stream>>>(cnt, N);
    count_deg<<<(E + 255) / 256, 256, 0, stream>>>(src, dst, cnt, E);
    partial_sum<<<nb, 256, 0, stream>>>(cnt, bsum, N);
    scan_bsums<<<1, 256, 0, stream>>>(bsum, rowptr + N, nb);
    write_rowptr<<<nb, 256, 0, stream>>>(cnt, bsum, rowptr, cursor, dinv, N);
    const int win = (N + NPASS - 1) / NPASS;
    for (int p = 0; p < NPASS; ++p) {
        int lo = p * win;
        int hi = lo + win; if (hi > N) hi = N;
        build_cols_win<<<(E + 255) / 256, 256, 0, stream>>>(src, dst, cursor, colidx, E, lo, hi);
    }

    const int spmm_blocks = (N * 64 + 255) / 256;
    const int gemm_blocks = (N + 31) / 32;

    // layer 1: bufA = Â x ; bufA = relu(bufA @ W0)  (in-place-safe GEMM)
    gather_spmm128<<<spmm_blocks, 256, 0, stream>>>(rowptr, colidx, dinv, x, bufA);
    gemm_rb<128, true><<<gemm_blocks, 256, 0, stream>>>(bufA, W0, bufA, N);

    // layer 2: bufB = bufA @ W1 ; out = Â bufB   (associativity: spmm(h)@W1 == Â(h@W1))
    gemm_rb<64, false><<<gemm_blocks, 256, 0, stream>>>(bufA, W1, bufB, N);
    gather_spmm64<<<spmm_blocks, 256, 0, stream>>>(rowptr, colidx, dinv, bufB, out);
}